// Round 6
// baseline (303.053 us; speedup 1.0000x reference)
//
#include <hip/hip_runtime.h>

#define RS2f 0.70710678118654752f

// DPP quad_perm encodings: sel0 | sel1<<2 | sel2<<4 | sel3<<6
#define QP_XOR1 0xB1   // [1,0,3,2]
#define QP_XOR2 0x4E   // [2,3,0,1]
#define QP_BC0  0x00
#define QP_BC1  0x55
#define QP_BC2  0xAA
#define QP_BC3  0xFF

template<int CTRL> __device__ __forceinline__ float dppf(float x) {
  return __int_as_float(__builtin_amdgcn_update_dpp(
      0, __float_as_int(x), CTRL, 0xF, 0xF, true));
}

__device__ __forceinline__ float sxor(float x, int sm) {
  return __int_as_float(__float_as_int(x) ^ sm);
}

// Build row0 of U = RZ(a4)RY(a3)RZ(a2)RY(a1)RZ(a0)·H.
// The RZ/RY chain is SU(2) [[α,β],[−β*,α*]]; track (α,β) only.
// U row0 = rs2·(α+β, α−β); row1 of U = (conj(w1), −conj(w0)) derived at apply.
__device__ __forceinline__ void build_gate(float a0, float a1, float a2, float a3, float a4,
                                           float &w0r, float &w0i, float &w1r, float &w1i) {
  float s, c;
  __sincosf(0.5f*a0, &s, &c);
  float ar = c, ai = -s, br = 0.f, bi = 0.f;     // S = RZ(a0)
  __sincosf(0.5f*a1, &s, &c);
  { float tar = c*ar + s*br, tai = c*ai - s*bi;
    float tbr = c*br - s*ar, tbi = c*bi + s*ai;
    ar=tar; ai=tai; br=tbr; bi=tbi; }
  __sincosf(0.5f*a2, &s, &c);
  { float t;
    t=ar; ar = c*t + s*ai; ai = c*ai - s*t;
    t=br; br = c*t + s*bi; bi = c*bi - s*t; }
  __sincosf(0.5f*a3, &s, &c);
  { float tar = c*ar + s*br, tai = c*ai - s*bi;
    float tbr = c*br - s*ar, tbi = c*bi + s*ai;
    ar=tar; ai=tai; br=tbr; bi=tbi; }
  __sincosf(0.5f*a4, &s, &c);
  { float t;
    t=ar; ar = c*t + s*ai; ai = c*ai - s*t;
    t=br; br = c*t + s*bi; bi = c*bi - s*t; }
  w0r = RS2f*(ar+br); w0i = RS2f*(ai+bi);
  w1r = RS2f*(ar-br); w1i = RS2f*(ai-bi);
}

__global__ void __launch_bounds__(256)
quanv_kernel(const float* __restrict__ x,
             const float* __restrict__ crz_t,
             const float* __restrict__ ry_t,
             const float* __restrict__ fc1_w,
             const float* __restrict__ fc1_b,
             const float* __restrict__ fc2_w,
             const float* __restrict__ fc2_b,
             float* __restrict__ out, int B)
{
  __shared__ float sw[20 * 784];
  const int tid = threadIdx.x;
  for (int i = tid; i < (20 * 784) / 4; i += 256)
    ((float4*)sw)[i] = ((const float4*)fc1_w)[i];
  __syncthreads();

  const int l = tid & 3;                       // lane within 4-lane group
  const int b = (blockIdx.x * 256 + tid) >> 2; // element id
  if (b >= B) return;
  const float* img = x + (size_t)b * 784;

  // ---- uniform scalar-derived constants ----
  const float theta = crz_t[0];
  const float ryt   = ry_t[0];
  float cry, sry;
  __sincosf(0.5f * ryt, &sry, &cry);
  const float sgn0 = (l & 2) ? sry : -sry;   // Ry wire0 partner sign (bit = l>>1)
  const float sgn1 = (l & 1) ? sry : -sry;   // Ry wire1 partner sign (bit = l&1)
  const int sm0 = (l & 2) ? (int)0x80000000 : 0;  // wire0 row-bit sign mask
  const int sm1 = (l & 1) ? (int)0x80000000 : 0;  // wire1 row-bit sign mask

  // CRZ ring diag exp(0.5i*theta*sg[n]) for this lane's 4 amps (n = 4l+k)
  float g0,g1,g2,g3;
  if      (l == 0) { g0= 0.f; g1=-1.f; g2=-1.f; g3=0.f; }
  else if (l == 1) { g0=-1.f; g1=-2.f; g2= 0.f; g3=1.f; }
  else if (l == 2) { g0=-1.f; g1= 0.f; g2=-2.f; g3=1.f; }
  else             { g0= 0.f; g1= 1.f; g2= 1.f; g3=4.f; }
  float czk[4], szk[4];
  __sincosf(0.5f*theta*g0, &szk[0], &czk[0]);
  __sincosf(0.5f*theta*g1, &szk[1], &czk[1]);
  __sincosf(0.5f*theta*g2, &szk[2], &czk[2]);
  __sincosf(0.5f*theta*g3, &szk[3], &czk[3]);

  // state: amp n = 4*l + k  (bits: b0=l>>1, b1=l&1, b2=k>>1, b3=k&1)
  float sr[4], si[4];
#pragma unroll
  for (int k = 0; k < 4; ++k) { sr[k] = 0.f; si[k] = 0.f; }
  if (l == 0) sr[0] = 1.f;

  float h1[5];
#pragma unroll
  for (int j = 0; j < 5; ++j) h1[j] = 0.f;
  const float* swl = sw + 5 * l * 784;

#pragma unroll 1
  for (int wi = 0; wi < 14; ++wi) {
    const int r0 = 2 * wi;
    const bool hFull = (wi != 13);             // valid rows: 4 or 2
    float P[4][4];
#pragma unroll
    for (int r = 0; r < 4; ++r) {
      if (r < (hFull ? 4 : 2)) {
        float4 v = *(const float4*)(img + (r0 + r) * 28);
        P[r][0]=v.x; P[r][1]=v.y; P[r][2]=v.z; P[r][3]=v.w;
      } else {
        P[r][0]=0.f; P[r][1]=0.f; P[r][2]=0.f; P[r][3]=0.f;
      }
    }

    float Wc0, Wc1, Wc2, Wc3;                  // gate for window wj-1 (pipeline reg)

#pragma unroll 1
    for (int wj = 0; wj <= 14; ++wj) {
      float Wn0 = 0.f, Wn1 = 0.f, Wn2 = 0.f, Wn3 = 0.f;

      // ---- STAGE A (wj<14): slide P, pick angles, build gate for window wj ----
      if (wj < 14) {
        if (wj > 0) {
#pragma unroll
          for (int r = 0; r < 4; ++r) { P[r][0] = P[r][2]; P[r][1] = P[r][3]; }
          const int c0 = 2 * wj + 2;
          if (c0 < 28) {
#pragma unroll
            for (int r = 0; r < 4; ++r) {
              if (r < (hFull ? 4 : 2)) {
                float2 v = *(const float2*)(img + (r0 + r) * 28 + c0);
                P[r][2] = v.x; P[r][3] = v.y;
              } else { P[r][2] = 0.f; P[r][3] = 0.f; }
            }
          } else {
#pragma unroll
            for (int r = 0; r < 4; ++r) { P[r][2] = 0.f; P[r][3] = 0.f; }
          }
        }
        const bool wFull = (wj != 13);

        // per-lane angle pick: lane l gets packed f[5l..5l+4]
        float a0=0.f, a1=0.f, a2=0.f, a3=0.f, a4=0.f;
        if (hFull && wFull) {
          if      (l == 0) { a0=P[0][0]; a1=P[0][1]; a2=P[0][2]; a3=P[0][3]; a4=P[1][0]; }
          else if (l == 1) { a0=P[1][1]; a1=P[1][2]; a2=P[1][3]; a3=P[2][0]; a4=P[2][1]; }
          else if (l == 2) { a0=P[2][2]; a1=P[2][3]; a2=P[3][0]; a3=P[3][1]; a4=P[3][2]; }
          else             { a0=P[3][3]; }
        } else if (hFull) {                    // w==2
          if      (l == 0) { a0=P[0][0]; a1=P[0][1]; a2=P[1][0]; a3=P[1][1]; a4=P[2][0]; }
          else if (l == 1) { a0=P[2][1]; a1=P[3][0]; a2=P[3][1]; }
        } else if (wFull) {                    // h==2
          if      (l == 0) { a0=P[0][0]; a1=P[0][1]; a2=P[0][2]; a3=P[0][3]; a4=P[1][0]; }
          else if (l == 1) { a0=P[1][1]; a1=P[1][2]; a2=P[1][3]; }
        } else {                               // h==2, w==2
          if      (l == 0) { a0=P[0][0]; a1=P[0][1]; a2=P[1][0]; a3=P[1][1]; }
        }

        build_gate(a0, a1, a2, a3, a4, Wn0, Wn1, Wn2, Wn3);
      }

      // ---- STAGE B (wj>0): apply gate Wc (window wj-1) + fold fc1 ----
      if (wj > 0) {
        // wire 0 (partner lane^2, row bit = l>>1)
        {
          float w0r = dppf<QP_BC0>(Wc0), w0i = dppf<QP_BC0>(Wc1);
          float w1r = dppf<QP_BC0>(Wc2), w1i = dppf<QP_BC0>(Wc3);
          float uar = sxor(w0r, sm0), uai = w0i;
          float ubr = w1r,            ubi = sxor(w1i, sm0);
#pragma unroll
          for (int k = 0; k < 4; ++k) {
            float pr = dppf<QP_XOR2>(sr[k]), pi = dppf<QP_XOR2>(si[k]);
            float ar = sr[k], ai = si[k];
            sr[k] = uar*ar - uai*ai + ubr*pr - ubi*pi;
            si[k] = uar*ai + uai*ar + ubr*pi + ubi*pr;
          }
        }
        // wire 1 (partner lane^1, row bit = l&1)
        {
          float w0r = dppf<QP_BC1>(Wc0), w0i = dppf<QP_BC1>(Wc1);
          float w1r = dppf<QP_BC1>(Wc2), w1i = dppf<QP_BC1>(Wc3);
          float uar = sxor(w0r, sm1), uai = w0i;
          float ubr = w1r,            ubi = sxor(w1i, sm1);
#pragma unroll
          for (int k = 0; k < 4; ++k) {
            float pr = dppf<QP_XOR1>(sr[k]), pi = dppf<QP_XOR1>(si[k]);
            float ar = sr[k], ai = si[k];
            sr[k] = uar*ar - uai*ai + ubr*pr - ubi*pi;
            si[k] = uar*ai + uai*ar + ubr*pi + ubi*pr;
          }
        }
        // wire 2 (local pairs (k,k+2)): lo'=w0·lo+w1·hi ; hi'=conj(w1)·lo−conj(w0)·hi
        {
          float w0r = dppf<QP_BC2>(Wc0), w0i = dppf<QP_BC2>(Wc1);
          float w1r = dppf<QP_BC2>(Wc2), w1i = dppf<QP_BC2>(Wc3);
#pragma unroll
          for (int k = 0; k < 2; ++k) {
            float lr = sr[k], li = si[k], hr = sr[k+2], hi = si[k+2];
            sr[k]   = w0r*lr - w0i*li + w1r*hr - w1i*hi;
            si[k]   = w0r*li + w0i*lr + w1r*hi + w1i*hr;
            sr[k+2] = w1r*lr + w1i*li - w0r*hr - w0i*hi;
            si[k+2] = w1r*li - w1i*lr - w0r*hi + w0i*hr;
          }
        }
        // wire 3 (local pairs (k,k+1))
        {
          float w0r = dppf<QP_BC3>(Wc0), w0i = dppf<QP_BC3>(Wc1);
          float w1r = dppf<QP_BC3>(Wc2), w1i = dppf<QP_BC3>(Wc3);
#pragma unroll
          for (int k = 0; k < 4; k += 2) {
            float lr = sr[k], li = si[k], hr = sr[k+1], hi = si[k+1];
            sr[k]   = w0r*lr - w0i*li + w1r*hr - w1i*hi;
            si[k]   = w0r*li + w0i*lr + w1r*hi + w1i*hr;
            sr[k+1] = w1r*lr + w1i*li - w0r*hr - w0i*hi;
            si[k+1] = w1r*li - w1i*lr - w0r*hi + w0i*hr;
          }
        }

        // CRZ ring diagonal
#pragma unroll
        for (int k = 0; k < 4; ++k) {
          float r = sr[k], im = si[k];
          sr[k] = czk[k]*r - szk[k]*im;
          si[k] = czk[k]*im + szk[k]*r;
        }

        // Ry(ryt) wires 0,1 (cross-lane)
#pragma unroll
        for (int k = 0; k < 4; ++k) {
          float pr = dppf<QP_XOR2>(sr[k]), pi = dppf<QP_XOR2>(si[k]);
          sr[k] = cry*sr[k] + sgn0*pr;
          si[k] = cry*si[k] + sgn0*pi;
        }
#pragma unroll
        for (int k = 0; k < 4; ++k) {
          float pr = dppf<QP_XOR1>(sr[k]), pi = dppf<QP_XOR1>(si[k]);
          sr[k] = cry*sr[k] + sgn1*pr;
          si[k] = cry*si[k] + sgn1*pi;
        }
        // Ry wires 2,3 (local)
#pragma unroll
        for (int k = 0; k < 2; ++k) {
          float ar=sr[k], br=sr[k+2];  sr[k]=cry*ar - sry*br;  sr[k+2]=sry*ar + cry*br;
          float ai=si[k], bi=si[k+2];  si[k]=cry*ai - sry*bi;  si[k+2]=sry*ai + cry*bi;
        }
#pragma unroll
        for (int k = 0; k < 4; k += 2) {
          float ar=sr[k], br=sr[k+1];  sr[k]=cry*ar - sry*br;  sr[k+1]=sry*ar + cry*br;
          float ai=si[k], bi=si[k+1];  si[k]=cry*ai - sry*bi;  si[k+1]=sry*ai + cry*bi;
        }

        // Z expectations + quad butterfly
        float p0 = sr[0]*sr[0] + si[0]*si[0];
        float p1 = sr[1]*sr[1] + si[1]*si[1];
        float p2 = sr[2]*sr[2] + si[2]*si[2];
        float p3 = sr[3]*sr[3] + si[3]*si[3];
        float s01 = p0 + p1, s23 = p2 + p3;
        float t   = s01 + s23;
        float o0 = sxor(t, sm0);
        float o1 = sxor(t, sm1);
        float o2 = s01 - s23;
        float o3 = (p0 - p1) + (p2 - p3);
        o0 += dppf<QP_XOR1>(o0); o0 += dppf<QP_XOR2>(o0);
        o1 += dppf<QP_XOR1>(o1); o1 += dppf<QP_XOR2>(o1);
        o2 += dppf<QP_XOR1>(o2); o2 += dppf<QP_XOR2>(o2);
        o3 += dppf<QP_XOR1>(o3); o3 += dppf<QP_XOR2>(o3);

        // fc1 partial: this lane's 5 rows, window (wi, wj-1)
        const int win4 = (wi * 14 + (wj - 1)) * 4;
#pragma unroll
        for (int j = 0; j < 5; ++j) {
          float4 wv = *(const float4*)(swl + j * 784 + win4);
          h1[j] = fmaf(wv.x, o0, fmaf(wv.y, o1, fmaf(wv.z, o2, fmaf(wv.w, o3, h1[j]))));
        }
      }

      // rotate pipeline register
      if (wj < 14) { Wc0 = Wn0; Wc1 = Wn1; Wc2 = Wn2; Wc3 = Wn3; }
    }
  }

  // ---- epilogue: bias + leaky relu + fc2, reduce over group ----
  float pa = 0.f, pb = 0.f;
#pragma unroll
  for (int j = 0; j < 5; ++j) {
    const int r = 5 * l + j;
    float v = h1[j] + fc1_b[r];
    v = (v > 0.f) ? v : 0.1f * v;
    pa = fmaf(fc2_w[r],      v, pa);
    pb = fmaf(fc2_w[20 + r], v, pb);
  }
  pa += dppf<QP_XOR1>(pa); pa += dppf<QP_XOR2>(pa);
  pb += dppf<QP_XOR1>(pb); pb += dppf<QP_XOR2>(pb);
  if (l == 0) {
    float2 res; res.x = pa + fc2_b[0]; res.y = pb + fc2_b[1];
    *(float2*)(out + (size_t)b * 2) = res;
  }
}

extern "C" void kernel_launch(void* const* d_in, const int* in_sizes, int n_in,
                              void* d_out, int out_size, void* d_ws, size_t ws_size,
                              hipStream_t stream) {
  const float* x      = (const float*)d_in[0];
  const float* crz_t  = (const float*)d_in[1];
  const float* ry_t   = (const float*)d_in[2];
  const float* fc1_w  = (const float*)d_in[3];
  const float* fc1_b  = (const float*)d_in[4];
  const float* fc2_w  = (const float*)d_in[5];
  const float* fc2_b  = (const float*)d_in[6];
  float* out = (float*)d_out;
  const int B = in_sizes[0] / 784;
  const int grid = (B * 4 + 255) / 256;
  quanv_kernel<<<grid, 256, 0, stream>>>(x, crz_t, ry_t, fc1_w, fc1_b,
                                         fc2_w, fc2_b, out, B);
}

// Round 7
// 252.402 us; speedup vs baseline: 1.2007x; 1.2007x over previous
//
#include <hip/hip_runtime.h>

#define RS2f 0.70710678118654752f

// DPP quad_perm encodings: sel0 | sel1<<2 | sel2<<4 | sel3<<6
#define QP_XOR1 0xB1   // [1,0,3,2]
#define QP_XOR2 0x4E   // [2,3,0,1]
#define QP_BC0  0x00
#define QP_BC1  0x55
#define QP_BC2  0xAA
#define QP_BC3  0xFF

template<int CTRL> __device__ __forceinline__ float dppf(float x) {
  return __int_as_float(__builtin_amdgcn_update_dpp(
      0, __float_as_int(x), CTRL, 0xF, 0xF, true));
}

__device__ __forceinline__ float sxor(float x, int sm) {
  return __int_as_float(__float_as_int(x) ^ sm);
}

// Build row0 of U = RZ(a4)RY(a3)RZ(a2)RY(a1)RZ(a0)·H.  (verified r4/r5)
// The RZ/RY chain is SU(2) [[α,β],[−β*,α*]]; track (α,β) only.
// U row0 = rs2·(α+β, α−β); row1 of U = (conj(w1), −conj(w0)) derived at apply.
__device__ __forceinline__ void build_gate(float a0, float a1, float a2, float a3, float a4,
                                           float &w0r, float &w0i, float &w1r, float &w1i) {
  float s, c;
  __sincosf(0.5f*a0, &s, &c);
  float ar = c, ai = -s, br = 0.f, bi = 0.f;
  __sincosf(0.5f*a1, &s, &c);
  { float tar = c*ar + s*br, tai = c*ai - s*bi;
    float tbr = c*br - s*ar, tbi = c*bi + s*ai;
    ar=tar; ai=tai; br=tbr; bi=tbi; }
  __sincosf(0.5f*a2, &s, &c);
  { float t;
    t=ar; ar = c*t + s*ai; ai = c*ai - s*t;
    t=br; br = c*t + s*bi; bi = c*bi - s*t; }
  __sincosf(0.5f*a3, &s, &c);
  { float tar = c*ar + s*br, tai = c*ai - s*bi;
    float tbr = c*br - s*ar, tbi = c*bi + s*ai;
    ar=tar; ai=tai; br=tbr; bi=tbi; }
  __sincosf(0.5f*a4, &s, &c);
  { float t;
    t=ar; ar = c*t + s*ai; ai = c*ai - s*t;
    t=br; br = c*t + s*bi; bi = c*bi - s*t; }
  w0r = RS2f*(ar+br); w0i = RS2f*(ai+bi);
  w1r = RS2f*(ar-br); w1i = RS2f*(ai-bi);
}

// Full window angle pick (h=4, w=4) — ternary cndmask chains, no exec-mask blocks.
#define PICK_FULL                                                            \
  a0 = l0 ? P[0][0] : l1 ? P[1][1] : l2 ? P[2][2] : P[3][3];                 \
  a1 = l0 ? P[0][1] : l1 ? P[1][2] : l2 ? P[2][3] : 0.f;                     \
  a2 = l0 ? P[0][2] : l1 ? P[1][3] : l2 ? P[3][0] : 0.f;                     \
  a3 = l0 ? P[0][3] : l1 ? P[2][0] : l2 ? P[3][1] : 0.f;                     \
  a4 = l0 ? P[1][0] : l1 ? P[2][1] : l2 ? P[3][2] : 0.f;

// h=4, w=2 (last column of windows): f = P00,P01,P10,P11,P20,P21,P30,P31
#define PICK_W2                                                              \
  a0 = l0 ? P[0][0] : l1 ? P[2][1] : 0.f;                                    \
  a1 = l0 ? P[0][1] : l1 ? P[3][0] : 0.f;                                    \
  a2 = l0 ? P[1][0] : l1 ? P[3][1] : 0.f;                                    \
  a3 = l0 ? P[1][1] : 0.f;                                                   \
  a4 = l0 ? P[2][0] : 0.f;

// h=2, w=4 (last row of windows): f = P00..P03,P10..P13
#define PICK_H2                                                              \
  a0 = l0 ? P[0][0] : l1 ? P[1][1] : 0.f;                                    \
  a1 = l0 ? P[0][1] : l1 ? P[1][2] : 0.f;                                    \
  a2 = l0 ? P[0][2] : l1 ? P[1][3] : 0.f;                                    \
  a3 = l0 ? P[0][3] : 0.f;                                                   \
  a4 = l0 ? P[1][0] : 0.f;

// h=2, w=2 (corner): f = P00,P01,P10,P11
#define PICK_22                                                              \
  a0 = l0 ? P[0][0] : 0.f;                                                   \
  a1 = l0 ? P[0][1] : 0.f;                                                   \
  a2 = l0 ? P[1][0] : 0.f;                                                   \
  a3 = l0 ? P[1][1] : 0.f;                                                   \
  a4 = 0.f;

// Apply gate (Wc0..Wc3) to state + CRZ + Ry layer + Z expectations + fc1 fold.
// Verified math from round 5. Straight-line; lives in the same BB as build_gate.
#define APPLY_AND_FOLD(WIN) do {                                             \
  { float w0r = dppf<QP_BC0>(Wc0), w0i = dppf<QP_BC0>(Wc1);                  \
    float w1r = dppf<QP_BC0>(Wc2), w1i = dppf<QP_BC0>(Wc3);                  \
    float uar = sxor(w0r, sm0), uai = w0i;                                   \
    float ubr = w1r,            ubi = sxor(w1i, sm0);                        \
    _Pragma("unroll")                                                        \
    for (int k = 0; k < 4; ++k) {                                            \
      float pr = dppf<QP_XOR2>(sr[k]), pi = dppf<QP_XOR2>(si[k]);            \
      float ar = sr[k], ai = si[k];                                          \
      sr[k] = uar*ar - uai*ai + ubr*pr - ubi*pi;                             \
      si[k] = uar*ai + uai*ar + ubr*pi + ubi*pr;                             \
    } }                                                                      \
  { float w0r = dppf<QP_BC1>(Wc0), w0i = dppf<QP_BC1>(Wc1);                  \
    float w1r = dppf<QP_BC1>(Wc2), w1i = dppf<QP_BC1>(Wc3);                  \
    float uar = sxor(w0r, sm1), uai = w0i;                                   \
    float ubr = w1r,            ubi = sxor(w1i, sm1);                        \
    _Pragma("unroll")                                                        \
    for (int k = 0; k < 4; ++k) {                                            \
      float pr = dppf<QP_XOR1>(sr[k]), pi = dppf<QP_XOR1>(si[k]);            \
      float ar = sr[k], ai = si[k];                                          \
      sr[k] = uar*ar - uai*ai + ubr*pr - ubi*pi;                             \
      si[k] = uar*ai + uai*ar + ubr*pi + ubi*pr;                             \
    } }                                                                      \
  { float w0r = dppf<QP_BC2>(Wc0), w0i = dppf<QP_BC2>(Wc1);                  \
    float w1r = dppf<QP_BC2>(Wc2), w1i = dppf<QP_BC2>(Wc3);                  \
    _Pragma("unroll")                                                        \
    for (int k = 0; k < 2; ++k) {                                            \
      float lr = sr[k], li = si[k], hr = sr[k+2], hi = si[k+2];              \
      sr[k]   = w0r*lr - w0i*li + w1r*hr - w1i*hi;                           \
      si[k]   = w0r*li + w0i*lr + w1r*hi + w1i*hr;                           \
      sr[k+2] = w1r*lr + w1i*li - w0r*hr - w0i*hi;                           \
      si[k+2] = w1r*li - w1i*lr - w0r*hi + w0i*hr;                           \
    } }                                                                      \
  { float w0r = dppf<QP_BC3>(Wc0), w0i = dppf<QP_BC3>(Wc1);                  \
    float w1r = dppf<QP_BC3>(Wc2), w1i = dppf<QP_BC3>(Wc3);                  \
    _Pragma("unroll")                                                        \
    for (int k = 0; k < 4; k += 2) {                                         \
      float lr = sr[k], li = si[k], hr = sr[k+1], hi = si[k+1];              \
      sr[k]   = w0r*lr - w0i*li + w1r*hr - w1i*hi;                           \
      si[k]   = w0r*li + w0i*lr + w1r*hi + w1i*hr;                           \
      sr[k+1] = w1r*lr + w1i*li - w0r*hr - w0i*hi;                           \
      si[k+1] = w1r*li - w1i*lr - w0r*hi + w0i*hr;                           \
    } }                                                                      \
  _Pragma("unroll")                                                          \
  for (int k = 0; k < 4; ++k) {                                              \
    float r_ = sr[k], im_ = si[k];                                           \
    sr[k] = czk[k]*r_ - szk[k]*im_;                                          \
    si[k] = czk[k]*im_ + szk[k]*r_;                                          \
  }                                                                          \
  _Pragma("unroll")                                                          \
  for (int k = 0; k < 4; ++k) {                                              \
    float pr = dppf<QP_XOR2>(sr[k]), pi = dppf<QP_XOR2>(si[k]);              \
    sr[k] = cry*sr[k] + sgn0*pr;                                             \
    si[k] = cry*si[k] + sgn0*pi;                                             \
  }                                                                          \
  _Pragma("unroll")                                                          \
  for (int k = 0; k < 4; ++k) {                                              \
    float pr = dppf<QP_XOR1>(sr[k]), pi = dppf<QP_XOR1>(si[k]);              \
    sr[k] = cry*sr[k] + sgn1*pr;                                             \
    si[k] = cry*si[k] + sgn1*pi;                                             \
  }                                                                          \
  _Pragma("unroll")                                                          \
  for (int k = 0; k < 2; ++k) {                                              \
    float ar=sr[k], br2=sr[k+2]; sr[k]=cry*ar - sry*br2; sr[k+2]=sry*ar + cry*br2; \
    float ai=si[k], bi2=si[k+2]; si[k]=cry*ai - sry*bi2; si[k+2]=sry*ai + cry*bi2; \
  }                                                                          \
  _Pragma("unroll")                                                          \
  for (int k = 0; k < 4; k += 2) {                                           \
    float ar=sr[k], br2=sr[k+1]; sr[k]=cry*ar - sry*br2; sr[k+1]=sry*ar + cry*br2; \
    float ai=si[k], bi2=si[k+1]; si[k]=cry*ai - sry*bi2; si[k+1]=sry*ai + cry*bi2; \
  }                                                                          \
  { float p0 = sr[0]*sr[0] + si[0]*si[0];                                    \
    float p1 = sr[1]*sr[1] + si[1]*si[1];                                    \
    float p2 = sr[2]*sr[2] + si[2]*si[2];                                    \
    float p3 = sr[3]*sr[3] + si[3]*si[3];                                    \
    float s01 = p0 + p1, s23 = p2 + p3;                                      \
    float t_  = s01 + s23;                                                   \
    float o0 = sxor(t_, sm0);                                                \
    float o1 = sxor(t_, sm1);                                                \
    float o2 = s01 - s23;                                                    \
    float o3 = (p0 - p1) + (p2 - p3);                                        \
    o0 += dppf<QP_XOR1>(o0); o0 += dppf<QP_XOR2>(o0);                        \
    o1 += dppf<QP_XOR1>(o1); o1 += dppf<QP_XOR2>(o1);                        \
    o2 += dppf<QP_XOR1>(o2); o2 += dppf<QP_XOR2>(o2);                        \
    o3 += dppf<QP_XOR1>(o3); o3 += dppf<QP_XOR2>(o3);                        \
    const int win4_ = (WIN) * 4;                                             \
    _Pragma("unroll")                                                        \
    for (int j = 0; j < 5; ++j) {                                            \
      float4 wv = *(const float4*)(swl + j * 784 + win4_);                   \
      h1[j] = fmaf(wv.x, o0, fmaf(wv.y, o1, fmaf(wv.z, o2, fmaf(wv.w, o3, h1[j])))); \
    } }                                                                      \
} while (0)

#define ROTATE_W  Wc0 = Wn0; Wc1 = Wn1; Wc2 = Wn2; Wc3 = Wn3;

__global__ void __launch_bounds__(256)
quanv_kernel(const float* __restrict__ x,
             const float* __restrict__ crz_t,
             const float* __restrict__ ry_t,
             const float* __restrict__ fc1_w,
             const float* __restrict__ fc1_b,
             const float* __restrict__ fc2_w,
             const float* __restrict__ fc2_b,
             float* __restrict__ out, int B)
{
  __shared__ float sw[20 * 784];
  const int tid = threadIdx.x;
  for (int i = tid; i < (20 * 784) / 4; i += 256)
    ((float4*)sw)[i] = ((const float4*)fc1_w)[i];
  __syncthreads();

  const int l = tid & 3;                       // lane within 4-lane group
  const int b = (blockIdx.x * 256 + tid) >> 2; // element id
  if (b >= B) return;
  const float* img = x + (size_t)b * 784;
  const bool l0 = (l == 0), l1 = (l == 1), l2 = (l == 2);

  // ---- uniform scalar-derived constants ----
  const float theta = crz_t[0];
  const float ryt   = ry_t[0];
  float cry, sry;
  __sincosf(0.5f * ryt, &sry, &cry);
  const float sgn0 = (l & 2) ? sry : -sry;
  const float sgn1 = (l & 1) ? sry : -sry;
  const int sm0 = (l & 2) ? (int)0x80000000 : 0;
  const int sm1 = (l & 1) ? (int)0x80000000 : 0;

  float g0,g1,g2,g3;
  if      (l == 0) { g0= 0.f; g1=-1.f; g2=-1.f; g3=0.f; }
  else if (l == 1) { g0=-1.f; g1=-2.f; g2= 0.f; g3=1.f; }
  else if (l == 2) { g0=-1.f; g1= 0.f; g2=-2.f; g3=1.f; }
  else             { g0= 0.f; g1= 1.f; g2= 1.f; g3=4.f; }
  float czk[4], szk[4];
  __sincosf(0.5f*theta*g0, &szk[0], &czk[0]);
  __sincosf(0.5f*theta*g1, &szk[1], &czk[1]);
  __sincosf(0.5f*theta*g2, &szk[2], &czk[2]);
  __sincosf(0.5f*theta*g3, &szk[3], &czk[3]);

  float sr[4], si[4];
#pragma unroll
  for (int k = 0; k < 4; ++k) { sr[k] = 0.f; si[k] = 0.f; }
  if (l == 0) sr[0] = 1.f;

  float h1[5];
#pragma unroll
  for (int j = 0; j < 5; ++j) h1[j] = 0.f;
  const float* swl = sw + 5 * l * 784;

  float P[4][4];
  float a0, a1, a2, a3, a4;
  float Wc0, Wc1, Wc2, Wc3, Wn0, Wn1, Wn2, Wn3;

  // ================= main rows: wi = 0..12 (h = 4 always) =================
#pragma unroll 1
  for (int wi = 0; wi < 13; ++wi) {
    const float* imgw = img + (2 * wi) * 28;

    // peel wj = 0: fresh load + build only
#pragma unroll
    for (int r = 0; r < 4; ++r) {
      float4 v = *(const float4*)(imgw + r * 28);
      P[r][0]=v.x; P[r][1]=v.y; P[r][2]=v.z; P[r][3]=v.w;
    }
    PICK_FULL;
    build_gate(a0, a1, a2, a3, a4, Wc0, Wc1, Wc2, Wc3);

    // hot loop: wj = 1..12 — branch-free body, build(wj) ‖ apply(wj-1)
#pragma unroll 1
    for (int wj = 1; wj <= 12; ++wj) {
      const int c0 = 2 * wj + 2;                 // 4..26, always in-bounds
#pragma unroll
      for (int r = 0; r < 4; ++r) {
        P[r][0] = P[r][2]; P[r][1] = P[r][3];
        float2 v = *(const float2*)(imgw + r * 28 + c0);
        P[r][2] = v.x; P[r][3] = v.y;
      }
      PICK_FULL;
      build_gate(a0, a1, a2, a3, a4, Wn0, Wn1, Wn2, Wn3);
      APPLY_AND_FOLD(wi * 14 + wj - 1);
      ROTATE_W;
    }

    // peel wj = 13: zero-fill slide, w=2 pick, build ‖ apply(12), then apply(13)
#pragma unroll
    for (int r = 0; r < 4; ++r) {
      P[r][0] = P[r][2]; P[r][1] = P[r][3]; P[r][2] = 0.f; P[r][3] = 0.f;
    }
    PICK_W2;
    build_gate(a0, a1, a2, a3, a4, Wn0, Wn1, Wn2, Wn3);
    APPLY_AND_FOLD(wi * 14 + 12);
    ROTATE_W;
    APPLY_AND_FOLD(wi * 14 + 13);
  }

  // ================= tail row: wi = 13 (h = 2; P rows 2,3 stay zero) =================
  {
    const float* imgw = img + 26 * 28;
#pragma unroll
    for (int r = 0; r < 2; ++r) {
      float4 v = *(const float4*)(imgw + r * 28);
      P[r][0]=v.x; P[r][1]=v.y; P[r][2]=v.z; P[r][3]=v.w;
    }
#pragma unroll
    for (int r = 2; r < 4; ++r) { P[r][0]=0.f; P[r][1]=0.f; P[r][2]=0.f; P[r][3]=0.f; }
    PICK_H2;
    build_gate(a0, a1, a2, a3, a4, Wc0, Wc1, Wc2, Wc3);

#pragma unroll 1
    for (int wj = 1; wj <= 12; ++wj) {
      const int c0 = 2 * wj + 2;
      P[0][0]=P[0][2]; P[0][1]=P[0][3];
      P[1][0]=P[1][2]; P[1][1]=P[1][3];
      float2 v0 = *(const float2*)(imgw + c0);       P[0][2]=v0.x; P[0][3]=v0.y;
      float2 v1 = *(const float2*)(imgw + 28 + c0);  P[1][2]=v1.x; P[1][3]=v1.y;
      PICK_H2;
      build_gate(a0, a1, a2, a3, a4, Wn0, Wn1, Wn2, Wn3);
      APPLY_AND_FOLD(182 + wj - 1);
      ROTATE_W;
    }

    P[0][0]=P[0][2]; P[0][1]=P[0][3]; P[0][2]=0.f; P[0][3]=0.f;
    P[1][0]=P[1][2]; P[1][1]=P[1][3]; P[1][2]=0.f; P[1][3]=0.f;
    PICK_22;
    build_gate(a0, a1, a2, a3, a4, Wn0, Wn1, Wn2, Wn3);
    APPLY_AND_FOLD(182 + 12);
    ROTATE_W;
    APPLY_AND_FOLD(182 + 13);
  }

  // ---- epilogue: bias + leaky relu + fc2, reduce over group ----
  float pa = 0.f, pb = 0.f;
#pragma unroll
  for (int j = 0; j < 5; ++j) {
    const int r = 5 * l + j;
    float v = h1[j] + fc1_b[r];
    v = (v > 0.f) ? v : 0.1f * v;
    pa = fmaf(fc2_w[r],      v, pa);
    pb = fmaf(fc2_w[20 + r], v, pb);
  }
  pa += dppf<QP_XOR1>(pa); pa += dppf<QP_XOR2>(pa);
  pb += dppf<QP_XOR1>(pb); pb += dppf<QP_XOR2>(pb);
  if (l == 0) {
    float2 res; res.x = pa + fc2_b[0]; res.y = pb + fc2_b[1];
    *(float2*)(out + (size_t)b * 2) = res;
  }
}

extern "C" void kernel_launch(void* const* d_in, const int* in_sizes, int n_in,
                              void* d_out, int out_size, void* d_ws, size_t ws_size,
                              hipStream_t stream) {
  const float* x      = (const float*)d_in[0];
  const float* crz_t  = (const float*)d_in[1];
  const float* ry_t   = (const float*)d_in[2];
  const float* fc1_w  = (const float*)d_in[3];
  const float* fc1_b  = (const float*)d_in[4];
  const float* fc2_w  = (const float*)d_in[5];
  const float* fc2_b  = (const float*)d_in[6];
  float* out = (float*)d_out;
  const int B = in_sizes[0] / 784;
  const int grid = (B * 4 + 255) / 256;
  quanv_kernel<<<grid, 256, 0, stream>>>(x, crz_t, ry_t, fc1_w, fc1_b,
                                         fc2_w, fc2_b, out, B);
}

// Round 8
// 225.043 us; speedup vs baseline: 1.3466x; 1.1216x over previous
//
#include <hip/hip_runtime.h>

#define RS2f 0.70710678118654752f

// DPP quad_perm encodings: sel0 | sel1<<2 | sel2<<4 | sel3<<6
#define QP_XOR1 0xB1   // [1,0,3,2]
#define QP_XOR2 0x4E   // [2,3,0,1]
#define QP_BC0  0x00
#define QP_BC1  0x55
#define QP_BC2  0xAA
#define QP_BC3  0xFF

typedef float v2f __attribute__((ext_vector_type(2)));

template<int CTRL> __device__ __forceinline__ float dppf(float x) {
  return __int_as_float(__builtin_amdgcn_update_dpp(
      0, __float_as_int(x), CTRL, 0xF, 0xF, true));
}
template<int CTRL> __device__ __forceinline__ v2f dpp2(v2f v) {
  v2f r; r.x = dppf<CTRL>(v.x); r.y = dppf<CTRL>(v.y); return r;
}

__device__ __forceinline__ float sxor(float x, int sm) {
  return __int_as_float(__float_as_int(x) ^ sm);
}
__device__ __forceinline__ v2f vsplat(float a) { v2f r; r.x = a; r.y = a; return r; }
__device__ __forceinline__ v2f vperp(v2f v) { v2f r; r.x = -v.y; r.y = v.x; return r; }  //  i*v
__device__ __forceinline__ v2f vperc(v2f v) { v2f r; r.x = v.y; r.y = -v.x; return r; }  // -i*v
__device__ __forceinline__ v2f vfma2(float a, v2f b, v2f c) {
  return __builtin_elementwise_fma(vsplat(a), b, c);
}
__device__ __forceinline__ v2f vmul2(float a, v2f b) { return vsplat(a) * b; }

// Closed-form row0 of U = RZ(a4)RY(a3)RZ(a2)RY(a1)RZ(a0)·H.
// Middle M = RY(a3)RZ(a2)RY(a1):
//   m00 = ( cos(bp)cos(c), -cos(bm)sin(c) ),  m01 = ( -sin(bp)cos(c), sin(bm)sin(c) )
//   with bp=(a1+a3)/2, bm=(a1-a3)/2, c=a2/2.
// S = RZ(a4)·M·RZ(a0):  alpha = m00·e^{-i(a0+a4)/2},  beta = m01·e^{+i(a0-a4)/2}.
// U row0 = rs2·(alpha+beta, alpha-beta); row1 = (conj(w1), -conj(w0)) at apply.
// 5 independent sincos (short critical path) — algebra verified vs iterative build.
__device__ __forceinline__ void build_gate(float a0, float a1, float a2, float a3, float a4,
                                           float &w0r, float &w0i, float &w1r, float &w1i) {
  float sBp, cBp, sBm, cBm, sC, cC, sP, cP, sM, cM;
  __sincosf(0.5f * (a1 + a3), &sBp, &cBp);
  __sincosf(0.5f * (a1 - a3), &sBm, &cBm);
  __sincosf(0.5f * a2,        &sC,  &cC);
  __sincosf(0.5f * (a0 + a4), &sP,  &cP);
  __sincosf(0.5f * (a0 - a4), &sM,  &cM);
  float m00r =  cBp * cC, m00i = -cBm * sC;
  float m01r = -sBp * cC, m01i =  sBm * sC;
  float alr = fmaf(m00r, cP,  m00i * sP);   // alpha = m00 * (cP - i sP)
  float ali = fmaf(m00i, cP, -m00r * sP);
  float ber = fmaf(m01r, cM, -m01i * sM);   // beta  = m01 * (cM + i sM)
  float bei = fmaf(m01i, cM,  m01r * sM);
  w0r = RS2f * (alr + ber); w0i = RS2f * (ali + bei);
  w1r = RS2f * (alr - ber); w1i = RS2f * (ali - bei);
}

// Full window angle pick (h=4, w=4) — ternary cndmask chains, no exec-mask blocks.
#define PICK_FULL                                                            \
  a0 = l0 ? P[0][0] : l1 ? P[1][1] : l2 ? P[2][2] : P[3][3];                 \
  a1 = l0 ? P[0][1] : l1 ? P[1][2] : l2 ? P[2][3] : 0.f;                     \
  a2 = l0 ? P[0][2] : l1 ? P[1][3] : l2 ? P[3][0] : 0.f;                     \
  a3 = l0 ? P[0][3] : l1 ? P[2][0] : l2 ? P[3][1] : 0.f;                     \
  a4 = l0 ? P[1][0] : l1 ? P[2][1] : l2 ? P[3][2] : 0.f;

// h=4, w=2 (last column of windows): f = P00,P01,P10,P11,P20,P21,P30,P31
#define PICK_W2                                                              \
  a0 = l0 ? P[0][0] : l1 ? P[2][1] : 0.f;                                    \
  a1 = l0 ? P[0][1] : l1 ? P[3][0] : 0.f;                                    \
  a2 = l0 ? P[1][0] : l1 ? P[3][1] : 0.f;                                    \
  a3 = l0 ? P[1][1] : 0.f;                                                   \
  a4 = l0 ? P[2][0] : 0.f;

// h=2, w=4 (last row of windows): f = P00..P03,P10..P13
#define PICK_H2                                                              \
  a0 = l0 ? P[0][0] : l1 ? P[1][1] : 0.f;                                    \
  a1 = l0 ? P[0][1] : l1 ? P[1][2] : 0.f;                                    \
  a2 = l0 ? P[0][2] : l1 ? P[1][3] : 0.f;                                    \
  a3 = l0 ? P[0][3] : 0.f;                                                   \
  a4 = l0 ? P[1][0] : 0.f;

// h=2, w=2 (corner): f = P00,P01,P10,P11
#define PICK_22                                                              \
  a0 = l0 ? P[0][0] : 0.f;                                                   \
  a1 = l0 ? P[0][1] : 0.f;                                                   \
  a2 = l0 ? P[1][0] : 0.f;                                                   \
  a3 = l0 ? P[1][1] : 0.f;                                                   \
  a4 = 0.f;

// Apply gate (Wc0..Wc3) + CRZ + Ry layer + Z expectations + fc1 fold.
// Packed-f32 complex math (v_pk_fma_f32 targets); verified scalar math from r5.
#define APPLY_AND_FOLD(WIN) do {                                             \
  /* wire 0 (partner lane^2, row bit = l>>1) */                              \
  { float w0r = dppf<QP_BC0>(Wc0), w0i = dppf<QP_BC0>(Wc1);                  \
    float w1r = dppf<QP_BC0>(Wc2), w1i = dppf<QP_BC0>(Wc3);                  \
    float uar = sxor(w0r, sm0), uai = w0i;                                   \
    float ubr = w1r,            ubi = sxor(w1i, sm0);                        \
    _Pragma("unroll")                                                        \
    for (int k = 0; k < 4; ++k) {                                            \
      v2f p = dpp2<QP_XOR2>(s[k]);                                           \
      v2f a = s[k];                                                          \
      s[k] = vfma2(uar, a, vfma2(uai, vperp(a),                              \
                   vfma2(ubr, p, vmul2(ubi, vperp(p)))));                    \
    } }                                                                      \
  /* wire 1 (partner lane^1, row bit = l&1) */                               \
  { float w0r = dppf<QP_BC1>(Wc0), w0i = dppf<QP_BC1>(Wc1);                  \
    float w1r = dppf<QP_BC1>(Wc2), w1i = dppf<QP_BC1>(Wc3);                  \
    float uar = sxor(w0r, sm1), uai = w0i;                                   \
    float ubr = w1r,            ubi = sxor(w1i, sm1);                        \
    _Pragma("unroll")                                                        \
    for (int k = 0; k < 4; ++k) {                                            \
      v2f p = dpp2<QP_XOR1>(s[k]);                                           \
      v2f a = s[k];                                                          \
      s[k] = vfma2(uar, a, vfma2(uai, vperp(a),                              \
                   vfma2(ubr, p, vmul2(ubi, vperp(p)))));                    \
    } }                                                                      \
  /* wire 2 (local pairs (k,k+2)): lo'=w0.lo+w1.hi ; hi'=conj(w1).lo-conj(w0).hi */ \
  { float w0r = dppf<QP_BC2>(Wc0), w0i = dppf<QP_BC2>(Wc1);                  \
    float w1r = dppf<QP_BC2>(Wc2), w1i = dppf<QP_BC2>(Wc3);                  \
    float nw0r = -w0r, nw0i = -w0i;                                          \
    _Pragma("unroll")                                                        \
    for (int k = 0; k < 2; ++k) {                                            \
      v2f lo = s[k], hi = s[k+2];                                            \
      s[k]   = vfma2(w0r, lo, vfma2(w0i, vperp(lo),                          \
                     vfma2(w1r, hi, vmul2(w1i, vperp(hi)))));                \
      s[k+2] = vfma2(w1r, lo, vfma2(w1i, vperc(lo),                          \
                     vfma2(nw0r, hi, vmul2(nw0i, vperc(hi)))));              \
    } }                                                                      \
  /* wire 3 (local pairs (k,k+1)) */                                         \
  { float w0r = dppf<QP_BC3>(Wc0), w0i = dppf<QP_BC3>(Wc1);                  \
    float w1r = dppf<QP_BC3>(Wc2), w1i = dppf<QP_BC3>(Wc3);                  \
    float nw0r = -w0r, nw0i = -w0i;                                          \
    _Pragma("unroll")                                                        \
    for (int k = 0; k < 4; k += 2) {                                         \
      v2f lo = s[k], hi = s[k+1];                                            \
      s[k]   = vfma2(w0r, lo, vfma2(w0i, vperp(lo),                          \
                     vfma2(w1r, hi, vmul2(w1i, vperp(hi)))));                \
      s[k+1] = vfma2(w1r, lo, vfma2(w1i, vperc(lo),                          \
                     vfma2(nw0r, hi, vmul2(nw0i, vperc(hi)))));              \
    } }                                                                      \
  /* CRZ ring diagonal: s *= (cz + i sz) */                                  \
  _Pragma("unroll")                                                          \
  for (int k = 0; k < 4; ++k)                                                \
    s[k] = vfma2(czk[k], s[k], vmul2(szk[k], vperp(s[k])));                  \
  /* Ry wires 0,1 (cross-lane) */                                            \
  _Pragma("unroll")                                                          \
  for (int k = 0; k < 4; ++k) {                                              \
    v2f p = dpp2<QP_XOR2>(s[k]);                                             \
    s[k] = vfma2(cry, s[k], vmul2(sgn0, p));                                 \
  }                                                                          \
  _Pragma("unroll")                                                          \
  for (int k = 0; k < 4; ++k) {                                              \
    v2f p = dpp2<QP_XOR1>(s[k]);                                             \
    s[k] = vfma2(cry, s[k], vmul2(sgn1, p));                                 \
  }                                                                          \
  /* Ry wires 2,3 (local) */                                                 \
  _Pragma("unroll")                                                          \
  for (int k = 0; k < 2; ++k) {                                              \
    v2f lo = s[k], hi = s[k+2];                                              \
    s[k]   = vfma2(cry, lo, vmul2(nsry, hi));                                \
    s[k+2] = vfma2(sry, lo, vmul2(cry, hi));                                 \
  }                                                                          \
  _Pragma("unroll")                                                          \
  for (int k = 0; k < 4; k += 2) {                                           \
    v2f lo = s[k], hi = s[k+1];                                              \
    s[k]   = vfma2(cry, lo, vmul2(nsry, hi));                                \
    s[k+1] = vfma2(sry, lo, vmul2(cry, hi));                                 \
  }                                                                          \
  /* Z expectations + quad butterfly */                                      \
  { v2f q0 = s[0]*s[0], q1 = s[1]*s[1], q2 = s[2]*s[2], q3 = s[3]*s[3];      \
    float p0 = q0.x + q0.y, p1 = q1.x + q1.y;                                \
    float p2 = q2.x + q2.y, p3 = q3.x + q3.y;                                \
    float s01 = p0 + p1, s23 = p2 + p3;                                      \
    float t_  = s01 + s23;                                                   \
    float o0 = sxor(t_, sm0);                                                \
    float o1 = sxor(t_, sm1);                                                \
    float o2 = s01 - s23;                                                    \
    float o3 = (p0 - p1) + (p2 - p3);                                        \
    o0 += dppf<QP_XOR1>(o0); o0 += dppf<QP_XOR2>(o0);                        \
    o1 += dppf<QP_XOR1>(o1); o1 += dppf<QP_XOR2>(o1);                        \
    o2 += dppf<QP_XOR1>(o2); o2 += dppf<QP_XOR2>(o2);                        \
    o3 += dppf<QP_XOR1>(o3); o3 += dppf<QP_XOR2>(o3);                        \
    const int win4_ = (WIN) * 4;                                             \
    _Pragma("unroll")                                                        \
    for (int j = 0; j < 5; ++j) {                                            \
      float4 wv = *(const float4*)(swl + j * 784 + win4_);                   \
      h1[j] = fmaf(wv.x, o0, fmaf(wv.y, o1, fmaf(wv.z, o2, fmaf(wv.w, o3, h1[j])))); \
    } }                                                                      \
} while (0)

#define ROTATE_W  Wc0 = Wn0; Wc1 = Wn1; Wc2 = Wn2; Wc3 = Wn3;

__global__ void __launch_bounds__(256)
quanv_kernel(const float* __restrict__ x,
             const float* __restrict__ crz_t,
             const float* __restrict__ ry_t,
             const float* __restrict__ fc1_w,
             const float* __restrict__ fc1_b,
             const float* __restrict__ fc2_w,
             const float* __restrict__ fc2_b,
             float* __restrict__ out, int B)
{
  __shared__ float sw[20 * 784];
  const int tid = threadIdx.x;
  for (int i = tid; i < (20 * 784) / 4; i += 256)
    ((float4*)sw)[i] = ((const float4*)fc1_w)[i];
  __syncthreads();

  const int l = tid & 3;                       // lane within 4-lane group
  const int b = (blockIdx.x * 256 + tid) >> 2; // element id
  if (b >= B) return;
  const float* img = x + (size_t)b * 784;
  const bool l0 = (l == 0), l1 = (l == 1), l2 = (l == 2);

  // ---- uniform scalar-derived constants ----
  const float theta = crz_t[0];
  const float ryt   = ry_t[0];
  float cry, sry;
  __sincosf(0.5f * ryt, &sry, &cry);
  const float nsry = -sry;
  const float sgn0 = (l & 2) ? sry : -sry;
  const float sgn1 = (l & 1) ? sry : -sry;
  const int sm0 = (l & 2) ? (int)0x80000000 : 0;
  const int sm1 = (l & 1) ? (int)0x80000000 : 0;

  float g0,g1,g2,g3;
  if      (l == 0) { g0= 0.f; g1=-1.f; g2=-1.f; g3=0.f; }
  else if (l == 1) { g0=-1.f; g1=-2.f; g2= 0.f; g3=1.f; }
  else if (l == 2) { g0=-1.f; g1= 0.f; g2=-2.f; g3=1.f; }
  else             { g0= 0.f; g1= 1.f; g2= 1.f; g3=4.f; }
  float czk[4], szk[4];
  __sincosf(0.5f*theta*g0, &szk[0], &czk[0]);
  __sincosf(0.5f*theta*g1, &szk[1], &czk[1]);
  __sincosf(0.5f*theta*g2, &szk[2], &czk[2]);
  __sincosf(0.5f*theta*g3, &szk[3], &czk[3]);

  // state: amp n = 4*l + k; s[k] = (re, im) packed
  v2f s[4];
#pragma unroll
  for (int k = 0; k < 4; ++k) { s[k].x = 0.f; s[k].y = 0.f; }
  if (l == 0) s[0].x = 1.f;

  float h1[5];
#pragma unroll
  for (int j = 0; j < 5; ++j) h1[j] = 0.f;
  const float* swl = sw + 5 * l * 784;

  float P[4][4];
  float a0, a1, a2, a3, a4;
  float Wc0, Wc1, Wc2, Wc3, Wn0, Wn1, Wn2, Wn3;

  // ================= main rows: wi = 0..12 (h = 4 always) =================
#pragma unroll 1
  for (int wi = 0; wi < 13; ++wi) {
    const float* imgw = img + (2 * wi) * 28;

    // peel wj = 0: fresh load + build only
#pragma unroll
    for (int r = 0; r < 4; ++r) {
      float4 v = *(const float4*)(imgw + r * 28);
      P[r][0]=v.x; P[r][1]=v.y; P[r][2]=v.z; P[r][3]=v.w;
    }
    PICK_FULL;
    build_gate(a0, a1, a2, a3, a4, Wc0, Wc1, Wc2, Wc3);

    // hot loop: wj = 1..12 — branch-free body, build(wj) || apply(wj-1)
#pragma unroll 1
    for (int wj = 1; wj <= 12; ++wj) {
      const int c0 = 2 * wj + 2;                 // 4..26, always in-bounds
#pragma unroll
      for (int r = 0; r < 4; ++r) {
        P[r][0] = P[r][2]; P[r][1] = P[r][3];
        float2 v = *(const float2*)(imgw + r * 28 + c0);
        P[r][2] = v.x; P[r][3] = v.y;
      }
      PICK_FULL;
      build_gate(a0, a1, a2, a3, a4, Wn0, Wn1, Wn2, Wn3);
      APPLY_AND_FOLD(wi * 14 + wj - 1);
      ROTATE_W;
    }

    // peel wj = 13: zero-fill slide, w=2 pick, build || apply(12), then apply(13)
#pragma unroll
    for (int r = 0; r < 4; ++r) {
      P[r][0] = P[r][2]; P[r][1] = P[r][3]; P[r][2] = 0.f; P[r][3] = 0.f;
    }
    PICK_W2;
    build_gate(a0, a1, a2, a3, a4, Wn0, Wn1, Wn2, Wn3);
    APPLY_AND_FOLD(wi * 14 + 12);
    ROTATE_W;
    APPLY_AND_FOLD(wi * 14 + 13);
  }

  // ================= tail row: wi = 13 (h = 2; P rows 2,3 stay zero) =================
  {
    const float* imgw = img + 26 * 28;
#pragma unroll
    for (int r = 0; r < 2; ++r) {
      float4 v = *(const float4*)(imgw + r * 28);
      P[r][0]=v.x; P[r][1]=v.y; P[r][2]=v.z; P[r][3]=v.w;
    }
#pragma unroll
    for (int r = 2; r < 4; ++r) { P[r][0]=0.f; P[r][1]=0.f; P[r][2]=0.f; P[r][3]=0.f; }
    PICK_H2;
    build_gate(a0, a1, a2, a3, a4, Wc0, Wc1, Wc2, Wc3);

#pragma unroll 1
    for (int wj = 1; wj <= 12; ++wj) {
      const int c0 = 2 * wj + 2;
      P[0][0]=P[0][2]; P[0][1]=P[0][3];
      P[1][0]=P[1][2]; P[1][1]=P[1][3];
      float2 v0 = *(const float2*)(imgw + c0);       P[0][2]=v0.x; P[0][3]=v0.y;
      float2 v1 = *(const float2*)(imgw + 28 + c0);  P[1][2]=v1.x; P[1][3]=v1.y;
      PICK_H2;
      build_gate(a0, a1, a2, a3, a4, Wn0, Wn1, Wn2, Wn3);
      APPLY_AND_FOLD(182 + wj - 1);
      ROTATE_W;
    }

    P[0][0]=P[0][2]; P[0][1]=P[0][3]; P[0][2]=0.f; P[0][3]=0.f;
    P[1][0]=P[1][2]; P[1][1]=P[1][3]; P[1][2]=0.f; P[1][3]=0.f;
    PICK_22;
    build_gate(a0, a1, a2, a3, a4, Wn0, Wn1, Wn2, Wn3);
    APPLY_AND_FOLD(182 + 12);
    ROTATE_W;
    APPLY_AND_FOLD(182 + 13);
  }

  // ---- epilogue: bias + leaky relu + fc2, reduce over group ----
  float pa = 0.f, pb = 0.f;
#pragma unroll
  for (int j = 0; j < 5; ++j) {
    const int r = 5 * l + j;
    float v = h1[j] + fc1_b[r];
    v = (v > 0.f) ? v : 0.1f * v;
    pa = fmaf(fc2_w[r],      v, pa);
    pb = fmaf(fc2_w[20 + r], v, pb);
  }
  pa += dppf<QP_XOR1>(pa); pa += dppf<QP_XOR2>(pa);
  pb += dppf<QP_XOR1>(pb); pb += dppf<QP_XOR2>(pb);
  if (l == 0) {
    float2 res; res.x = pa + fc2_b[0]; res.y = pb + fc2_b[1];
    *(float2*)(out + (size_t)b * 2) = res;
  }
}

extern "C" void kernel_launch(void* const* d_in, const int* in_sizes, int n_in,
                              void* d_out, int out_size, void* d_ws, size_t ws_size,
                              hipStream_t stream) {
  const float* x      = (const float*)d_in[0];
  const float* crz_t  = (const float*)d_in[1];
  const float* ry_t   = (const float*)d_in[2];
  const float* fc1_w  = (const float*)d_in[3];
  const float* fc1_b  = (const float*)d_in[4];
  const float* fc2_w  = (const float*)d_in[5];
  const float* fc2_b  = (const float*)d_in[6];
  float* out = (float*)d_out;
  const int B = in_sizes[0] / 784;
  const int grid = (B * 4 + 255) / 256;
  quanv_kernel<<<grid, 256, 0, stream>>>(x, crz_t, ry_t, fc1_w, fc1_b,
                                         fc2_w, fc2_b, out, B);
}